// Round 7
// baseline (164.535 us; speedup 1.0000x reference)
//
#include <hip/hip_runtime.h>

typedef unsigned short u16;
typedef unsigned int u32;
using short8  = __attribute__((ext_vector_type(8))) short;
using floatx4 = __attribute__((ext_vector_type(4))) float;

#define N_TOK   2048
#define D_MODEL 1024
#define D_INT   512
#define NE      8

// ws layout (bytes)
#define O_TOK    0          // int tok[8192]
#define O_WROW   32768      // float wrow[8192]
#define O_ACT    65536      // u16 Act[4608*512]

static __device__ inline u16 f2bf(float f) {
    u32 u = __builtin_bit_cast(u32, f);
    u = (u + 0x7fffu + ((u >> 16) & 1u)) >> 16;
    return (u16)u;
}
static __device__ inline u32 pack2(float a, float b) {
    return (u32)f2bf(a) | ((u32)f2bf(b) << 16);
}
static __device__ inline uint4 pack8(floatx4 a, floatx4 b) {
    uint4 o;
    o.x = pack2(a[0], a[1]); o.y = pack2(a[2], a[3]);
    o.z = pack2(b[0], b[1]); o.w = pack2(b[2], b[3]);
    return o;
}
static __device__ inline void glds16(const u16* g, u16* l) {
    __builtin_amdgcn_global_load_lds(
        (const __attribute__((address_space(1))) void*)g,
        (__attribute__((address_space(3))) void*)l, 16, 0, 0);
}

// [0,2048): route one token each (rank via scan of L2-resident indices);
// [2048,2560): zero d_out for gemm2's atomic combine. Row-pad quantum 64.
__global__ __launch_bounds__(256) void route_kernel(
    const float* __restrict__ wts, const int* __restrict__ indices,
    const int* __restrict__ counts,
    int* __restrict__ tok, float* __restrict__ wrow, float* __restrict__ out) {
    int b = blockIdx.x, tid = threadIdx.x;
    if (b >= 2048) {
        int z = b - 2048;
        floatx4* dst = reinterpret_cast<floatx4*>(out) + (size_t)z * 1024;
        #pragma unroll
        for (int i = 0; i < 4; i++) dst[i * 256 + tid] = (floatx4){0.f, 0.f, 0.f, 0.f};
        return;
    }
    int t = b;
    int off[NE];
    {
        int acc = 0;
        #pragma unroll
        for (int e = 0; e < NE; e++) { off[e] = acc; acc += ((counts[e] + 63) >> 6) << 6; }
    }
    int e0 = indices[2 * t], e1 = indices[2 * t + 1];
    __shared__ int s0, s1;
    if (tid == 0) { s0 = 0; s1 = 0; }
    __syncthreads();
    int c0 = 0, c1 = 0;
    const int4* ip = reinterpret_cast<const int4*>(indices);
    #pragma unroll
    for (int i = 0; i < 4; i++) {
        int4 vv = ip[tid * 4 + i];
        int q = tid * 16 + i * 4;
        c0 += (q + 0 < 2 * t && vv.x == e0) + (q + 1 < 2 * t && vv.y == e0)
            + (q + 2 < 2 * t && vv.z == e0) + (q + 3 < 2 * t && vv.w == e0);
        c1 += (q + 0 <= 2 * t && vv.x == e1) + (q + 1 <= 2 * t && vv.y == e1)
            + (q + 2 <= 2 * t && vv.z == e1) + (q + 3 <= 2 * t && vv.w == e1);
    }
    if (c0) atomicAdd(&s0, c0);
    if (c1) atomicAdd(&s1, c1);
    __syncthreads();
    if (tid == 0) {
        int r0 = off[e0] + s0;
        int r1 = off[e1] + s1;
        tok[r0] = t; tok[r1] = t;
        wrow[r0] = wts[2 * t]; wrow[r1] = wts[2 * t + 1];
    }
}

// GEMM1: x[tok[row]] (f32, converted in staging) * fc1[e]^T (f32, converted in
// staging); a = y*silu(z) -> Act bf16. 64-row x 64-g tile, BK=64, grid (8,72).
// LDS [row][8 slots x 8 u16], slot = kb ^ (row&7) — same swizzle as R5.
__global__ __launch_bounds__(256) void gemm1_kernel(
    const float* __restrict__ x, const float* __restrict__ fc1,
    u16* __restrict__ Act, const int* __restrict__ counts,
    const int* __restrict__ tok) {
    __shared__ u16 As[64 * 64];
    __shared__ u16 Bs[128 * 64];
    int tid = threadIdx.x;
    int soff[NE + 1];
    {
        int acc = 0;
        #pragma unroll
        for (int e2 = 0; e2 < NE; e2++) { soff[e2] = acc; acc += ((counts[e2] + 63) >> 6) << 6; }
        soff[NE] = acc;
    }
    int row0 = blockIdx.y * 64;
    if (row0 >= soff[NE]) return;
    int e = 0;
    while (soff[e + 1] <= row0) e++;
    int cnte = counts[e];
    int bx = blockIdx.x;
    const float* Be = fc1 + (size_t)e * 1024 * 1024;

    int lane = tid & 63, w = tid >> 6;
    int m0 = (w >> 1) * 32, n0 = (w & 1) * 32;
    int lr = lane & 15, kq = lane >> 4;

    // A staging: slots v0=tid, v1=tid+256 (r = v>>3, chunk kb = (v&7)^(r&7))
    int rA0 = tid >> 3, rA1 = rA0 + 32;
    int kbA0 = (tid & 7) ^ (rA0 & 7), kbA1 = (tid & 7) ^ (rA1 & 7);
    int tA0 = (row0 + rA0 - soff[e]) < cnte ? tok[row0 + rA0] : 0;
    int tA1 = (row0 + rA1 - soff[e]) < cnte ? tok[row0 + rA1] : 0;
    const float* gA0 = x + (size_t)tA0 * 1024 + kbA0 * 8;
    const float* gA1 = x + (size_t)tA1 * 1024 + kbA1 * 8;
    // B staging: 4 slots v = tid + j*256, r = v>>3 in [0,128)
    const float* gB[4];
    #pragma unroll
    for (int j = 0; j < 4; j++) {
        int v = tid + j * 256;
        int r = v >> 3, kb = (v & 7) ^ (r & 7);
        int grow = (r < 64) ? (bx * 64 + r) : (448 + bx * 64 + r);
        gB[j] = Be + (size_t)grow * 1024 + kb * 8;
    }

    floatx4 aY[2][2], aZ[2][2];
    #pragma unroll
    for (int i = 0; i < 2; i++)
        #pragma unroll
        for (int j = 0; j < 2; j++) {
            aY[i][j] = (floatx4){0.f, 0.f, 0.f, 0.f};
            aZ[i][j] = (floatx4){0.f, 0.f, 0.f, 0.f};
        }

    for (int k0 = 0; k0 < 1024; k0 += 64) {
        floatx4 a0l = *reinterpret_cast<const floatx4*>(gA0 + k0);
        floatx4 a0h = *reinterpret_cast<const floatx4*>(gA0 + k0 + 4);
        floatx4 a1l = *reinterpret_cast<const floatx4*>(gA1 + k0);
        floatx4 a1h = *reinterpret_cast<const floatx4*>(gA1 + k0 + 4);
        floatx4 bl[4], bh[4];
        #pragma unroll
        for (int j = 0; j < 4; j++) {
            bl[j] = *reinterpret_cast<const floatx4*>(gB[j] + k0);
            bh[j] = *reinterpret_cast<const floatx4*>(gB[j] + k0 + 4);
        }
        __syncthreads();   // previous iter's LDS reads complete
        *reinterpret_cast<uint4*>(&As[(size_t)tid * 8])         = pack8(a0l, a0h);
        *reinterpret_cast<uint4*>(&As[(size_t)(tid + 256) * 8]) = pack8(a1l, a1h);
        #pragma unroll
        for (int j = 0; j < 4; j++)
            *reinterpret_cast<uint4*>(&Bs[(size_t)(tid + j * 256) * 8]) = pack8(bl[j], bh[j]);
        __syncthreads();
        #pragma unroll
        for (int ks = 0; ks < 2; ks++) {
            int sw = ((ks * 4 + kq) ^ (lr & 7)) * 8;
            short8 af[2], by[2], bz[2];
            #pragma unroll
            for (int i = 0; i < 2; i++)
                af[i] = *reinterpret_cast<const short8*>(&As[(m0 + i * 16 + lr) * 64 + sw]);
            #pragma unroll
            for (int j = 0; j < 2; j++) {
                by[j] = *reinterpret_cast<const short8*>(&Bs[(n0 + j * 16 + lr) * 64 + sw]);
                bz[j] = *reinterpret_cast<const short8*>(&Bs[(64 + n0 + j * 16 + lr) * 64 + sw]);
            }
            #pragma unroll
            for (int i = 0; i < 2; i++)
                #pragma unroll
                for (int j = 0; j < 2; j++) {
                    aY[i][j] = __builtin_amdgcn_mfma_f32_16x16x32_bf16(af[i], by[j], aY[i][j], 0, 0, 0);
                    aZ[i][j] = __builtin_amdgcn_mfma_f32_16x16x32_bf16(af[i], bz[j], aZ[i][j], 0, 0, 0);
                }
        }
    }
    #pragma unroll
    for (int i = 0; i < 2; i++)
        #pragma unroll
        for (int j = 0; j < 2; j++) {
            floatx4 y = aY[i][j], z = aZ[i][j];
            #pragma unroll
            for (int r = 0; r < 4; r++) {
                float zz = z[r];
                float av = y[r] * (zz / (1.0f + __expf(-zz)));
                int m = m0 + i * 16 + kq * 4 + r;
                int g = bx * 64 + n0 + j * 16 + lr;
                Act[(size_t)(row0 + m) * D_INT + g] = f2bf(av);
            }
        }
}

// GEMM2: Act (bf16, glds16-staged) * fc2[e]^T (f32, VALU-converted in staging);
// fused combine via f32 atomics into zeroed out. 64-row x 128-d tile, BK=64.
__global__ __launch_bounds__(256) void gemm2_kernel(
    const u16* __restrict__ Act, const float* __restrict__ fc2,
    float* __restrict__ out, const int* __restrict__ counts,
    const int* __restrict__ tok, const float* __restrict__ wrow) {
    __shared__ u16 As[64 * 64];
    __shared__ u16 Bs[128 * 64];
    __shared__ int sTok[64];
    __shared__ float sW[64];
    int tid = threadIdx.x;
    int soff[NE + 1];
    {
        int acc = 0;
        #pragma unroll
        for (int e2 = 0; e2 < NE; e2++) { soff[e2] = acc; acc += ((counts[e2] + 63) >> 6) << 6; }
        soff[NE] = acc;
    }
    int row0 = blockIdx.y * 64;
    if (row0 >= soff[NE]) return;
    int e = 0;
    while (soff[e + 1] <= row0) e++;
    int bx = blockIdx.x;
    const u16* A  = Act + (size_t)row0 * 512;
    const float* Be = fc2 + (size_t)e * 1024 * 512;

    int lane = tid & 63, w = tid >> 6;
    int m0 = (w >> 1) * 32, n0 = (w & 1) * 64;
    int lr = lane & 15, kq = lane >> 4;

    const u16* gA[2]; int oA[2];
    #pragma unroll
    for (int j = 0; j < 2; j++) {
        int v = tid + j * 256;
        int r = v >> 3, kb = (v & 7) ^ (r & 7);
        gA[j] = A + (size_t)r * 512 + kb * 8;
        oA[j] = (w * 64 + j * 256) * 8;
    }
    const float* gB[4];
    #pragma unroll
    for (int j = 0; j < 4; j++) {
        int v = tid + j * 256;
        int r = v >> 3, kb = (v & 7) ^ (r & 7);
        gB[j] = Be + (size_t)(bx * 128 + r) * 512 + kb * 8;
    }

    floatx4 acc[2][4];
    #pragma unroll
    for (int i = 0; i < 2; i++)
        #pragma unroll
        for (int j = 0; j < 4; j++) acc[i][j] = (floatx4){0.f, 0.f, 0.f, 0.f};

    for (int k0 = 0; k0 < 512; k0 += 64) {
        floatx4 bl[4], bh[4];
        #pragma unroll
        for (int j = 0; j < 4; j++) {
            bl[j] = *reinterpret_cast<const floatx4*>(gB[j] + k0);
            bh[j] = *reinterpret_cast<const floatx4*>(gB[j] + k0 + 4);
        }
        __syncthreads();
        glds16(gA[0] + k0, &As[oA[0]]);
        glds16(gA[1] + k0, &As[oA[1]]);
        #pragma unroll
        for (int j = 0; j < 4; j++)
            *reinterpret_cast<uint4*>(&Bs[(size_t)(tid + j * 256) * 8]) = pack8(bl[j], bh[j]);
        __syncthreads();
        #pragma unroll
        for (int ks = 0; ks < 2; ks++) {
            int sw = ((ks * 4 + kq) ^ (lr & 7)) * 8;
            short8 af[2], bf[4];
            #pragma unroll
            for (int i = 0; i < 2; i++)
                af[i] = *reinterpret_cast<const short8*>(&As[(m0 + i * 16 + lr) * 64 + sw]);
            #pragma unroll
            for (int j = 0; j < 4; j++)
                bf[j] = *reinterpret_cast<const short8*>(&Bs[(n0 + j * 16 + lr) * 64 + sw]);
            #pragma unroll
            for (int i = 0; i < 2; i++)
                #pragma unroll
                for (int j = 0; j < 4; j++)
                    acc[i][j] = __builtin_amdgcn_mfma_f32_16x16x32_bf16(af[i], bf[j], acc[i][j], 0, 0, 0);
        }
    }
    if (tid < 64) {
        int g = row0 + tid;
        bool val = (g - soff[e]) < counts[e];
        sTok[tid] = val ? tok[g] : -1;
        sW[tid]   = val ? wrow[g] : 0.f;
    }
    __syncthreads();
    #pragma unroll
    for (int i = 0; i < 2; i++)
        #pragma unroll
        for (int r = 0; r < 4; r++) {
            int m = m0 + i * 16 + kq * 4 + r;
            int t = sTok[m];
            if (t >= 0) {
                float wgt = sW[m];
                float* dst = out + (size_t)t * D_MODEL + bx * 128;
                #pragma unroll
                for (int j = 0; j < 4; j++)
                    atomicAdd(dst + n0 + j * 16 + lr, wgt * acc[i][j][r]);
            }
        }
}

extern "C" void kernel_launch(void* const* d_in, const int* in_sizes, int n_in,
                              void* d_out, int out_size, void* d_ws, size_t ws_size,
                              hipStream_t stream) {
    const float* x       = (const float*)d_in[0];
    const float* wts     = (const float*)d_in[1];
    const int*   indices = (const int*)d_in[2];
    const int*   counts  = (const int*)d_in[3];
    const float* fc1     = (const float*)d_in[4];
    const float* fc2     = (const float*)d_in[5];
    float* out = (float*)d_out;
    char* ws = (char*)d_ws;

    int*   tok  = (int*)(ws + O_TOK);
    float* wrow = (float*)(ws + O_WROW);
    u16*   Act  = (u16*)(ws + O_ACT);

    route_kernel<<<2560, 256, 0, stream>>>(wts, indices, counts, tok, wrow, out);
    gemm1_kernel<<<dim3(8, 72), 256, 0, stream>>>(x, fc1, Act, counts, tok);
    gemm2_kernel<<<dim3(8, 72), 256, 0, stream>>>(Act, fc2, out, counts, tok, wrow);
}

// Round 8
// 154.460 us; speedup vs baseline: 1.0652x; 1.0652x over previous
//
#include <hip/hip_runtime.h>

typedef unsigned short u16;
typedef unsigned int u32;
using short8  = __attribute__((ext_vector_type(8))) short;
using floatx4 = __attribute__((ext_vector_type(4))) float;

#define N_TOK   2048
#define D_MODEL 1024
#define D_INT   512
#define NE      8

// ws layout (bytes)
#define O_TOK    0          // int tok[5120]
#define O_WROW   24576      // float wrow[5120]
#define O_XG     65536      // u16 Xg[5120*1024]
#define O_ACT    10551296   // u16 Act[5120*512]
#define O_FC1B   36765696   // u16 fc1b[8*1024*1024]
#define O_FC2B   53542912   // u16 fc2b[8*1024*512]

static __device__ inline u16 f2bf(float f) {
    u32 u = __builtin_bit_cast(u32, f);
    u = (u + 0x7fffu + ((u >> 16) & 1u)) >> 16;
    return (u16)u;
}
static __device__ inline u32 pack2(float a, float b) {
    return (u32)f2bf(a) | ((u32)f2bf(b) << 16);
}
static __device__ inline void glds16(const u16* g, u16* l) {
    __builtin_amdgcn_global_load_lds(
        (const __attribute__((address_space(1))) void*)g,
        (__attribute__((address_space(3))) void*)l, 16, 0, 0);
}

// Fused prep: [0,6144) convert weights f32->bf16; [6144,8192) route+gather one
// token each; [8192,8704) zero d_out. Row-pad quantum = 64.
__global__ __launch_bounds__(256) void prep_kernel(
    const float* __restrict__ x, const float* __restrict__ wts,
    const int* __restrict__ indices, const int* __restrict__ counts,
    const float* __restrict__ fc1, const float* __restrict__ fc2,
    u16* __restrict__ fc1b, u16* __restrict__ fc2b,
    u16* __restrict__ Xg, int* __restrict__ tok, float* __restrict__ wrow,
    float* __restrict__ out) {
    int b = blockIdx.x, tid = threadIdx.x;
    if (b < 6144) {
        size_t v = (size_t)b * 256 + tid;
        const float* src; u16* dst; size_t off;
        if (v < 1048576) { src = fc1; dst = fc1b; off = v * 8; }
        else             { src = fc2; dst = fc2b; off = (v - 1048576) * 8; }
        const floatx4* s4 = reinterpret_cast<const floatx4*>(src + off);
        floatx4 a = s4[0], bb = s4[1];
        uint4 o;
        o.x = pack2(a[0], a[1]); o.y = pack2(a[2], a[3]);
        o.z = pack2(bb[0], bb[1]); o.w = pack2(bb[2], bb[3]);
        *reinterpret_cast<uint4*>(dst + off) = o;
        return;
    }
    if (b < 8192) {
        int t = b - 6144;
        int off[NE];
        {
            int acc = 0;
            #pragma unroll
            for (int e = 0; e < NE; e++) { off[e] = acc; acc += ((counts[e] + 63) >> 6) << 6; }
        }
        int e0 = indices[2 * t], e1 = indices[2 * t + 1];
        __shared__ int s0, s1;
        if (tid == 0) { s0 = 0; s1 = 0; }
        __syncthreads();
        int c0 = 0, c1 = 0;
        const int4* ip = reinterpret_cast<const int4*>(indices);
        #pragma unroll
        for (int i = 0; i < 4; i++) {
            int4 vv = ip[tid * 4 + i];
            int q = tid * 16 + i * 4;
            c0 += (q + 0 < 2 * t && vv.x == e0) + (q + 1 < 2 * t && vv.y == e0)
                + (q + 2 < 2 * t && vv.z == e0) + (q + 3 < 2 * t && vv.w == e0);
            c1 += (q + 0 <= 2 * t && vv.x == e1) + (q + 1 <= 2 * t && vv.y == e1)
                + (q + 2 <= 2 * t && vv.z == e1) + (q + 3 <= 2 * t && vv.w == e1);
        }
        if (c0) atomicAdd(&s0, c0);
        if (c1) atomicAdd(&s1, c1);
        __syncthreads();
        int r0 = off[e0] + s0;
        int r1 = off[e1] + s1;
        if (tid == 0) {
            tok[r0] = t; tok[r1] = t;
            wrow[r0] = wts[2 * t]; wrow[r1] = wts[2 * t + 1];
        }
        const floatx4* src = reinterpret_cast<const floatx4*>(x + (size_t)t * D_MODEL);
        floatx4 a = src[tid];
        uint2 o;
        o.x = pack2(a[0], a[1]); o.y = pack2(a[2], a[3]);
        *reinterpret_cast<uint2*>(Xg + (size_t)r0 * D_MODEL + tid * 4) = o;
        *reinterpret_cast<uint2*>(Xg + (size_t)r1 * D_MODEL + tid * 4) = o;
        return;
    }
    {
        int z = b - 8192;
        floatx4* dst = reinterpret_cast<floatx4*>(out) + (size_t)z * 1024;
        #pragma unroll
        for (int i = 0; i < 4; i++) dst[i * 256 + tid] = (floatx4){0.f, 0.f, 0.f, 0.f};
        return;
    }
}

// GEMM1: 64-row x 64-g tile (y+z = 128 B-rows), BK=128 (8 barrier-drains
// instead of 16), grid (8,72). LDS [row][16 slots x 8 u16], slot = kb^(row&15):
// glds16 dest lane-contiguous, ds_read_b128 2-way banked (free).
__global__ __launch_bounds__(256) void gemm1_kernel(
    const u16* __restrict__ Xg, const u16* __restrict__ fc1b,
    u16* __restrict__ Act, const int* __restrict__ counts) {
    __shared__ u16 As[64 * 128];    // 16 KB
    __shared__ u16 Bs[128 * 128];   // 32 KB
    int tid = threadIdx.x;
    int soff[NE + 1];
    {
        int acc = 0;
        #pragma unroll
        for (int e2 = 0; e2 < NE; e2++) { soff[e2] = acc; acc += ((counts[e2] + 63) >> 6) << 6; }
        soff[NE] = acc;
    }
    int row0 = blockIdx.y * 64;
    if (row0 >= soff[NE]) return;
    int e = 0;
    while (soff[e + 1] <= row0) e++;
    int bx = blockIdx.x;
    const u16* A  = Xg + (size_t)row0 * 1024;
    const u16* Be = fc1b + (size_t)e * 1024 * 1024;

    int lane = tid & 63, w = tid >> 6;
    int m0 = (w >> 1) * 32, n0 = (w & 1) * 32;
    int lr = lane & 15, kq = lane >> 4;

    // A staging: 4 slots/thread. v = tid + p*256: r = v>>4, s = v&15, kb = s^(r&15)
    const u16* gA[4]; u16* lA[4];
    #pragma unroll
    for (int p = 0; p < 4; p++) {
        int v = tid + p * 256;
        int r = v >> 4, kb = (v & 15) ^ (r & 15);
        gA[p] = A + (size_t)r * 1024 + kb * 8;
        lA[p] = As + (size_t)(w * 64 + p * 256) * 8;
    }
    // B staging: 8 slots/thread. r in [0,128): y rows then z rows.
    const u16* gB[8]; u16* lB[8];
    #pragma unroll
    for (int p = 0; p < 8; p++) {
        int v = tid + p * 256;
        int r = v >> 4, kb = (v & 15) ^ (r & 15);
        int grow = (r < 64) ? (bx * 64 + r) : (448 + bx * 64 + r);
        gB[p] = Be + (size_t)grow * 1024 + kb * 8;
        lB[p] = Bs + (size_t)(w * 64 + p * 256) * 8;
    }

    floatx4 aY[2][2], aZ[2][2];
    #pragma unroll
    for (int i = 0; i < 2; i++)
        #pragma unroll
        for (int j = 0; j < 2; j++) {
            aY[i][j] = (floatx4){0.f, 0.f, 0.f, 0.f};
            aZ[i][j] = (floatx4){0.f, 0.f, 0.f, 0.f};
        }

    for (int k0 = 0; k0 < 1024; k0 += 128) {
        #pragma unroll
        for (int p = 0; p < 4; p++) glds16(gA[p] + k0, lA[p]);
        #pragma unroll
        for (int p = 0; p < 8; p++) glds16(gB[p] + k0, lB[p]);
        __syncthreads();
        #pragma unroll
        for (int ks = 0; ks < 4; ks++) {
            int sw = ((ks * 4 + kq) ^ lr) * 8;
            short8 af[2], by[2], bz[2];
            #pragma unroll
            for (int i = 0; i < 2; i++)
                af[i] = *reinterpret_cast<const short8*>(&As[(m0 + i * 16 + lr) * 128 + sw]);
            #pragma unroll
            for (int j = 0; j < 2; j++) {
                by[j] = *reinterpret_cast<const short8*>(&Bs[(n0 + j * 16 + lr) * 128 + sw]);
                bz[j] = *reinterpret_cast<const short8*>(&Bs[(64 + n0 + j * 16 + lr) * 128 + sw]);
            }
            #pragma unroll
            for (int i = 0; i < 2; i++)
                #pragma unroll
                for (int j = 0; j < 2; j++) {
                    aY[i][j] = __builtin_amdgcn_mfma_f32_16x16x32_bf16(af[i], by[j], aY[i][j], 0, 0, 0);
                    aZ[i][j] = __builtin_amdgcn_mfma_f32_16x16x32_bf16(af[i], bz[j], aZ[i][j], 0, 0, 0);
                }
        }
        __syncthreads();
    }
    #pragma unroll
    for (int i = 0; i < 2; i++)
        #pragma unroll
        for (int j = 0; j < 2; j++) {
            floatx4 y = aY[i][j], z = aZ[i][j];
            #pragma unroll
            for (int r = 0; r < 4; r++) {
                float zz = z[r];
                float av = y[r] * (zz / (1.0f + __expf(-zz)));
                int m = m0 + i * 16 + kq * 4 + r;
                int g = bx * 64 + n0 + j * 16 + lr;
                Act[(size_t)(row0 + m) * D_INT + g] = f2bf(av);
            }
        }
}

// GEMM2: 64-row x 128-d tile, BK=128 (4 drains), grid (8,72);
// fused combine via f32 atomics into zeroed out.
__global__ __launch_bounds__(256) void gemm2_kernel(
    const u16* __restrict__ Act, const u16* __restrict__ fc2b,
    float* __restrict__ out, const int* __restrict__ counts,
    const int* __restrict__ tok, const float* __restrict__ wrow) {
    __shared__ u16 As[64 * 128];
    __shared__ u16 Bs[128 * 128];
    __shared__ int sTok[64];
    __shared__ float sW[64];
    int tid = threadIdx.x;
    int soff[NE + 1];
    {
        int acc = 0;
        #pragma unroll
        for (int e2 = 0; e2 < NE; e2++) { soff[e2] = acc; acc += ((counts[e2] + 63) >> 6) << 6; }
        soff[NE] = acc;
    }
    int row0 = blockIdx.y * 64;
    if (row0 >= soff[NE]) return;
    int e = 0;
    while (soff[e + 1] <= row0) e++;
    int bx = blockIdx.x;
    const u16* A  = Act + (size_t)row0 * 512;
    const u16* Be = fc2b + (size_t)e * 1024 * 512;

    int lane = tid & 63, w = tid >> 6;
    int m0 = (w >> 1) * 32, n0 = (w & 1) * 64;
    int lr = lane & 15, kq = lane >> 4;

    const u16* gA[4]; u16* lA[4];
    #pragma unroll
    for (int p = 0; p < 4; p++) {
        int v = tid + p * 256;
        int r = v >> 4, kb = (v & 15) ^ (r & 15);
        gA[p] = A + (size_t)r * 512 + kb * 8;
        lA[p] = As + (size_t)(w * 64 + p * 256) * 8;
    }
    const u16* gB[8]; u16* lB[8];
    #pragma unroll
    for (int p = 0; p < 8; p++) {
        int v = tid + p * 256;
        int r = v >> 4, kb = (v & 15) ^ (r & 15);
        gB[p] = Be + (size_t)(bx * 128 + r) * 512 + kb * 8;
        lB[p] = Bs + (size_t)(w * 64 + p * 256) * 8;
    }

    floatx4 acc[2][4];
    #pragma unroll
    for (int i = 0; i < 2; i++)
        #pragma unroll
        for (int j = 0; j < 4; j++) acc[i][j] = (floatx4){0.f, 0.f, 0.f, 0.f};

    for (int k0 = 0; k0 < 512; k0 += 128) {
        #pragma unroll
        for (int p = 0; p < 4; p++) glds16(gA[p] + k0, lA[p]);
        #pragma unroll
        for (int p = 0; p < 8; p++) glds16(gB[p] + k0, lB[p]);
        __syncthreads();
        #pragma unroll
        for (int ks = 0; ks < 4; ks++) {
            int sw = ((ks * 4 + kq) ^ lr) * 8;
            short8 af[2], bf[4];
            #pragma unroll
            for (int i = 0; i < 2; i++)
                af[i] = *reinterpret_cast<const short8*>(&As[(m0 + i * 16 + lr) * 128 + sw]);
            #pragma unroll
            for (int j = 0; j < 4; j++)
                bf[j] = *reinterpret_cast<const short8*>(&Bs[(n0 + j * 16 + lr) * 128 + sw]);
            #pragma unroll
            for (int i = 0; i < 2; i++)
                #pragma unroll
                for (int j = 0; j < 4; j++)
                    acc[i][j] = __builtin_amdgcn_mfma_f32_16x16x32_bf16(af[i], bf[j], acc[i][j], 0, 0, 0);
        }
        __syncthreads();
    }
    if (tid < 64) {
        int g = row0 + tid;
        bool val = (g - soff[e]) < counts[e];
        sTok[tid] = val ? tok[g] : -1;
        sW[tid]   = val ? wrow[g] : 0.f;
    }
    __syncthreads();
    #pragma unroll
    for (int i = 0; i < 2; i++)
        #pragma unroll
        for (int r = 0; r < 4; r++) {
            int m = m0 + i * 16 + kq * 4 + r;
            int t = sTok[m];
            if (t >= 0) {
                float wgt = sW[m];
                float* dst = out + (size_t)t * D_MODEL + bx * 128;
                #pragma unroll
                for (int j = 0; j < 4; j++)
                    atomicAdd(dst + n0 + j * 16 + lr, wgt * acc[i][j][r]);
            }
        }
}

extern "C" void kernel_launch(void* const* d_in, const int* in_sizes, int n_in,
                              void* d_out, int out_size, void* d_ws, size_t ws_size,
                              hipStream_t stream) {
    const float* x       = (const float*)d_in[0];
    const float* wts     = (const float*)d_in[1];
    const int*   indices = (const int*)d_in[2];
    const int*   counts  = (const int*)d_in[3];
    const float* fc1     = (const float*)d_in[4];
    const float* fc2     = (const float*)d_in[5];
    float* out = (float*)d_out;
    char* ws = (char*)d_ws;

    int*   tok  = (int*)(ws + O_TOK);
    float* wrow = (float*)(ws + O_WROW);
    u16*   Xg   = (u16*)(ws + O_XG);
    u16*   Act  = (u16*)(ws + O_ACT);
    u16*   fc1b = (u16*)(ws + O_FC1B);
    u16*   fc2b = (u16*)(ws + O_FC2B);

    prep_kernel<<<8704, 256, 0, stream>>>(x, wts, indices, counts, fc1, fc2,
                                          fc1b, fc2b, Xg, tok, wrow, out);
    gemm1_kernel<<<dim3(8, 72), 256, 0, stream>>>(Xg, fc1b, Act, counts);
    gemm2_kernel<<<dim3(8, 72), 256, 0, stream>>>(Act, fc2b, out, counts, tok, wrow);
}